// Round 15
// baseline (3479.657 us; speedup 1.0000x reference)
//
#include <hip/hip_runtime.h>
#include <math.h>

#define NSTEPS 200
#define NT     512          // 8 waves; wave w owns output tile (rg=w>>2, cw=w&3)
#define BR     64
#define SQDT_F 0.07071067811865475f
#define DT_F   0.005f
#define LOSCL  4096.0f            // 2^12
#define LOINV  2.44140625e-4f     // 2^-12

typedef float  f32x16 __attribute__((ext_vector_type(16)));
typedef short  s16x8 __attribute__((ext_vector_type(8)));
typedef _Float16 h16x8 __attribute__((ext_vector_type(8)));
typedef unsigned short u16;
typedef unsigned short us4 __attribute__((ext_vector_type(4)));

// prepacked weight offsets in u16 units (each 128x128 matrix = 32768 u16 as hi/lo frags)
#define ENC_OFF 0
#define W1_OFF  32768
#define W2_OFF  65536
#define WG0_OFF 98304
#define WG1_OFF 131072
#define DEC_OFF 163840
#define WPK_TOT 196608

// ---- fp16 scaled two-term split: x ~= hi + lo*2^-12, |err| <= ~2^-23 |x| ----
__device__ __forceinline__ u16 f2h(float v) {
    _Float16 h = (_Float16)v;                       // v_cvt_f16_f32, RNE
    return __builtin_bit_cast(u16, h);
}
__device__ __forceinline__ float h2f(u16 u) {
    return (float)__builtin_bit_cast(_Float16, u);
}
__device__ __forceinline__ u16 split_hi(float v) { return f2h(v); }
__device__ __forceinline__ u16 split_lo(float v, u16 hi) {
    return f2h((v - h2f(hi)) * LOSCL);              // v-hi exact in fp32; *2^12 exact
}

// GELU via Abramowitz-Stegun 7.1.26 erf (max abs err 1.5e-7 — passed r14 at
// absmax 0.0078; tanh-GELU's 1e-3 failed r2).
__device__ __forceinline__ float gelu_fast(float x) {
    float ax = fabsf(x) * 0.70710678118654752f;     // |x|/sqrt(2)
    float t  = __builtin_amdgcn_rcpf(fmaf(0.3275911f, ax, 1.0f));
    float p  = fmaf(t, 1.061405429f, -1.453152027f);
    p = fmaf(t, p, 1.421413741f);
    p = fmaf(t, p, -0.284496736f);
    p = fmaf(t, p, 0.254829592f);
    p = p * t;
    float e  = __expf(-ax * ax);
    float er = fmaf(-p, e, 1.0f);
    er = copysignf(er, x);
    return 0.5f * x * (1.0f + er);
}

// MFMA via builtin: compiler models hazards (r6/r7 inline-asm MFMA NaN'd).
// 32x32x16: same operand regs as 16x16x32 (4+4 VGPR) but 2x FLOPs -> halves
// LDS A-traffic and L2 B-traffic per FLOP (r14 post-mortem: LDS read pipe is
// the limiter at 1536 b128/CU/step).
__device__ __forceinline__ void mfma32(f32x16& d, s16x8 a, s16x8 b) {
    d = __builtin_amdgcn_mfma_f32_32x32x16_f16(
            __builtin_bit_cast(h16x8, a), __builtin_bit_cast(h16x8, b), d, 0, 0, 0);
}
__device__ __forceinline__ s16x8 ldf(const u16* p) {
    return *reinterpret_cast<const s16x8*>(p);
}

// ---------------- weight prepack: fp32 -> fp16 hi / scaled-lo 32x32x16 B-frags ----
// frag layout: base + ((nt2*8 + kk)*2 + term)*512 + lane*8 + i   (u16 units)
// element: B[k = kk*16 + (lane>>5)*8 + i][n = nt2*32 + (lane&31)]
// sigma column-deinterleaved: WG0 = sig_w[:,0::2], WG1 = sig_w[:,1::2]
__global__ void prepack(const float* __restrict__ enc_w, const float* __restrict__ mu_w1,
                        const float* __restrict__ mu_w2, const float* __restrict__ sig_w,
                        const float* __restrict__ dec_w, u16* __restrict__ wpk)
{
    int u = blockIdx.x * 256 + threadIdx.x;
    if (u >= WPK_TOT) return;
    int mat  = u >> 15;
    int r    = u & 32767;
    int i    = r & 7;
    int lane = (r >> 3) & 63;
    int term = (r >> 9) & 1;
    int kk   = (r >> 10) & 7;
    int nt2  = (r >> 13) & 3;
    int k = kk * 16 + (lane >> 5) * 8 + i;
    int n = nt2 * 32 + (lane & 31);
    float v;
    switch (mat) {
        case 0:  v = enc_w[k * 128 + n];         break;
        case 1:  v = mu_w1[k * 128 + n];         break;
        case 2:  v = mu_w2[k * 128 + n];         break;
        case 3:  v = sig_w[k * 256 + 2 * n];     break;
        case 4:  v = sig_w[k * 256 + 2 * n + 1]; break;
        default: v = dec_w[k * 128 + n];         break;
    }
    u16 hi = split_hi(v);
    wpk[u] = term ? split_lo(v, hi) : hi;
}

// ---------------- main fused SDE kernel ----------------
// z/h stored in FRAGMENT ORDER: arr[rg*4096 + kk*512 + lane*8 + i] holds
// element (row = rg*32 + (lane&31), k = kk*16 + (lane>>5)*8 + i). A-reads are
// base + lane*16B — linear, conflict-free (r13/r14: conflicts were b128-count
// proportional in the row-major layout). Established invariants: no resident
// weights (L2 B-frags), asm "+s" LICM-blocker, MFMA builtin, fp16 hi/lo split.
__global__ __launch_bounds__(NT) void sde_mfma(
    const float* __restrict__ y, const float* __restrict__ noise,
    const float* __restrict__ enc_b, const float* __restrict__ mu_b1,
    const float* __restrict__ mu_b2, const float* __restrict__ sig_b,
    const float* __restrict__ dec_b, const u16* __restrict__ wpk,
    float* __restrict__ out, int Btot)
{
    __shared__ __align__(16) u16 zfh[8192];
    __shared__ __align__(16) u16 zfl[8192];
    __shared__ __align__(16) u16 hfh[8192];
    __shared__ __align__(16) u16 hfl[8192];
    __shared__ float nsb[2][128];

    const int tid  = threadIdx.x;
    const int lane = tid & 63, wid = tid >> 6;      // wid 0..7
    const int l31  = lane & 31, lg2 = lane >> 5;
    const int rg   = wid >> 2, cw = wid & 3;        // tile coords
    const size_t brow = (size_t)blockIdx.x * BR;

    const int n0 = cw * 32 + l31;                   // this thread's output col
    const float b10 = mu_b1[n0];
    const float b20 = mu_b2[n0];
    const float bg0 = sig_b[2 * n0];
    const float bg1 = sig_b[2 * n0 + 1];

    // write base for this thread's h/z elements (k-dim = n0 fixed):
    const int wbase = rg * 4096 + (n0 >> 4) * 512 + ((n0 >> 3) & 1) * 256 + (n0 & 7);
    // A-read base for this wave's row group:
    const int abase = rg * 4096 + (lane << 3);

    // ---- stage y into zf (fp16 hi/lo, fragment order) ----
    #pragma unroll
    for (int c = 0; c < 4; c++) {
        int q = c * NT + tid;                 // 0..2047
        int row = q >> 5, k4 = (q & 31) << 2;
        const float4 v = *reinterpret_cast<const float4*>(y + (brow + row) * 128 + k4);
        int addr = (row >> 5) * 4096 + (k4 >> 4) * 512
                 + ((row & 31) + ((k4 >> 3) & 1) * 32) * 8 + (k4 & 7);
        float vv[4] = {v.x, v.y, v.z, v.w};
        us4 hv, lv;
        #pragma unroll
        for (int e = 0; e < 4; e++) {
            u16 h = split_hi(vv[e]);
            u16 l = split_lo(vv[e], h);
            hv[e] = h; lv[e] = l;
        }
        *reinterpret_cast<us4*>(zfh + addr) = hv;
        *reinterpret_cast<us4*>(zfl + addr) = lv;
    }
    __syncthreads();

    float zr[16];   // z state, fp32, carried across all 200 steps (reg-indexed, unrolled)

    // ---- encoder: z0 = gelu(y @ enc_w + enc_b) ----
    {
        const float be0 = enc_b[n0];
        f32x16 a0, a1;
        #pragma unroll
        for (int g = 0; g < 16; g++) { a0[g] = be0; a1[g] = 0.0f; }
        #pragma unroll 2
        for (int kk = 0; kk < 8; kk++) {
            int ao = abase + kk * 512;
            s16x8 ah = ldf(zfh + ao), al = ldf(zfl + ao);
            int fo = (((cw << 3) | kk) << 10) + (lane << 3);
            s16x8 bh = ldf(wpk + ENC_OFF + fo);
            s16x8 bl = ldf(wpk + ENC_OFF + fo + 512);
            mfma32(a0, ah, bh);
            mfma32(a1, al, bh);
            mfma32(a1, ah, bl);
        }
        #pragma unroll
        for (int g = 0; g < 16; g++)
            zr[g] = gelu_fast(fmaf(a1[g], LOINV, a0[g]));
    }
    __syncthreads();   // all y-tile reads done

    // write z0 into zf; stage noise for t=0
    #pragma unroll
    for (int g = 0; g < 16; g++) {
        int rl = (g & 3) + 8 * (g >> 2) + 4 * lg2;
        u16 h = split_hi(zr[g]);
        zfh[wbase + rl * 8] = h;
        zfl[wbase + rl * 8] = split_lo(zr[g], h);
    }
    if (tid < 128) nsb[0][tid] = noise[brow * 2 + tid];
    __syncthreads();

    // loop-opaque weight pointer: defeats LICM hoisting weight loads into
    // loop-carried registers (the scratch-spill source in r5-r10).
    const u16* wq = wpk;

    // ---- 200 Euler-Maruyama steps, 2 barriers each ----
    for (int t = 0; t < NSTEPS; t++) {
        asm volatile("" : "+s"(wq));
        {   // prefetch next step's noise into the other buffer
            int tn = (t + 1 < NSTEPS) ? (t + 1) : t;
            if (tid < 128) nsb[(t + 1) & 1][tid] = noise[((size_t)tn * Btot + brow) * 2 + tid];
        }
        // pass 1 — G1: h = gelu(z @ W1 + b1) -> hf  (W1 from L2, 24 MFMA)
        {
            f32x16 a0, a1;
            #pragma unroll
            for (int g = 0; g < 16; g++) { a0[g] = b10; a1[g] = 0.0f; }
            #pragma unroll 2
            for (int kk = 0; kk < 8; kk++) {
                int ao = abase + kk * 512;
                s16x8 ah = ldf(zfh + ao), al = ldf(zfl + ao);
                int fo = (((cw << 3) | kk) << 10) + (lane << 3);
                s16x8 bh = ldf(wq + W1_OFF + fo);
                s16x8 bl = ldf(wq + W1_OFF + fo + 512);
                mfma32(a0, ah, bh);
                mfma32(a1, al, bh);
                mfma32(a1, ah, bl);
            }
            #pragma unroll
            for (int g = 0; g < 16; g++) {
                float hv = gelu_fast(fmaf(a1[g], LOINV, a0[g]));
                int rl = (g & 3) + 8 * (g >> 2) + 4 * lg2;
                u16 h = split_hi(hv);
                hfh[wbase + rl * 8] = h;
                hfl[wbase + rl * 8] = split_lo(hv, h);
            }
        }
        // pass 2 — sigma: zr += g0*dw0 + g1*dw1 (one A-sweep feeds both, 48 MFMA;
        // unroll 1 caps transients: accum 64 + zr 16 + A 8 + B 16 < 128 regs)
        {
            f32x16 q0h, q0l, q1h, q1l;
            #pragma unroll
            for (int g = 0; g < 16; g++) {
                q0h[g] = bg0; q0l[g] = 0.0f;
                q1h[g] = bg1; q1l[g] = 0.0f;
            }
            #pragma unroll 1
            for (int kk = 0; kk < 8; kk++) {
                int ao = abase + kk * 512;
                s16x8 ah = ldf(zfh + ao), al = ldf(zfl + ao);
                int fo = (((cw << 3) | kk) << 10) + (lane << 3);
                s16x8 b0h = ldf(wq + WG0_OFF + fo);
                s16x8 b0l = ldf(wq + WG0_OFF + fo + 512);
                s16x8 b1h = ldf(wq + WG1_OFF + fo);
                s16x8 b1l = ldf(wq + WG1_OFF + fo + 512);
                mfma32(q0h, ah, b0h);
                mfma32(q0l, al, b0h);
                mfma32(q0l, ah, b0l);
                mfma32(q1h, ah, b1h);
                mfma32(q1l, al, b1h);
                mfma32(q1l, ah, b1l);
            }
            const float* np = nsb[t & 1];
            #pragma unroll
            for (int g = 0; g < 16; g++) {
                int m = rg * 32 + (g & 3) + 8 * (g >> 2) + 4 * lg2;
                float dw0 = np[2 * m] * SQDT_F;
                float dw1 = np[2 * m + 1] * SQDT_F;
                float gv0 = fmaf(q0l[g], LOINV, q0h[g]);
                float gv1 = fmaf(q1l[g], LOINV, q1h[g]);
                zr[g] = fmaf(gv0, dw0, fmaf(gv1, dw1, zr[g]));
            }
        }
        __syncthreads();   // bar1: all zf reads done; hf visible

        // pass 3 — G2: drift = h @ W2 + b2; zr += drift*dt; rewrite zf (24 MFMA)
        {
            f32x16 a0, a1;
            #pragma unroll
            for (int g = 0; g < 16; g++) { a0[g] = b20; a1[g] = 0.0f; }
            #pragma unroll 2
            for (int kk = 0; kk < 8; kk++) {
                int ao = abase + kk * 512;
                s16x8 ah = ldf(hfh + ao), al = ldf(hfl + ao);
                int fo = (((cw << 3) | kk) << 10) + (lane << 3);
                s16x8 bh = ldf(wq + W2_OFF + fo);
                s16x8 bl = ldf(wq + W2_OFF + fo + 512);
                mfma32(a0, ah, bh);
                mfma32(a1, al, bh);
                mfma32(a1, ah, bl);
            }
            #pragma unroll
            for (int g = 0; g < 16; g++) {
                float drift = fmaf(a1[g], LOINV, a0[g]);
                float v = fmaf(drift, DT_F, zr[g]);
                zr[g] = v;
                int rl = (g & 3) + 8 * (g >> 2) + 4 * lg2;
                u16 h = split_hi(v);
                zfh[wbase + rl * 8] = h;
                zfl[wbase + rl * 8] = split_lo(v, h);
            }
        }
        __syncthreads();   // bar2: new zf visible
    }

    // ---- decoder: out = z @ dec_w + dec_b ----
    {
        const float bd0 = dec_b[n0];
        f32x16 a0, a1;
        #pragma unroll
        for (int g = 0; g < 16; g++) { a0[g] = bd0; a1[g] = 0.0f; }
        #pragma unroll 2
        for (int kk = 0; kk < 8; kk++) {
            int ao = abase + kk * 512;
            s16x8 ah = ldf(zfh + ao), al = ldf(zfl + ao);
            int fo = (((cw << 3) | kk) << 10) + (lane << 3);
            s16x8 bh = ldf(wpk + DEC_OFF + fo);
            s16x8 bl = ldf(wpk + DEC_OFF + fo + 512);
            mfma32(a0, ah, bh);
            mfma32(a1, al, bh);
            mfma32(a1, ah, bl);
        }
        #pragma unroll
        for (int g = 0; g < 16; g++) {
            int m = rg * 32 + (g & 3) + 8 * (g >> 2) + 4 * lg2;
            out[(brow + m) * 128 + n0] = fmaf(a1[g], LOINV, a0[g]);
        }
    }
}

extern "C" void kernel_launch(void* const* d_in, const int* in_sizes, int n_in,
                              void* d_out, int out_size, void* d_ws, size_t ws_size,
                              hipStream_t stream) {
    const float* y     = (const float*)d_in[0];
    const float* noise = (const float*)d_in[1];
    const float* enc_w = (const float*)d_in[2];
    const float* enc_b = (const float*)d_in[3];
    const float* mu_w1 = (const float*)d_in[4];
    const float* mu_b1 = (const float*)d_in[5];
    const float* mu_w2 = (const float*)d_in[6];
    const float* mu_b2 = (const float*)d_in[7];
    const float* sig_w = (const float*)d_in[8];
    const float* sig_b = (const float*)d_in[9];
    const float* dec_w = (const float*)d_in[10];
    const float* dec_b = (const float*)d_in[11];
    float* out = (float*)d_out;
    u16* wpk = (u16*)d_ws;

    const int Btot = in_sizes[0] / 128;     // 32768
    prepack<<<(WPK_TOT + 255) / 256, 256, 0, stream>>>(enc_w, mu_w1, mu_w2, sig_w, dec_w, wpk);
    sde_mfma<<<Btot / BR, NT, 0, stream>>>(y, noise, enc_b, mu_b1, mu_b2, sig_b, dec_b,
                                           wpk, out, Btot);
}